// Round 13
// baseline (112.028 us; speedup 1.0000x reference)
//
#include <hip/hip_runtime.h>
#include <hip/hip_bf16.h>

// ---------------------------------------------------------------------------
// LossNet: x (12288,128) fp32 -> scalar loss.  bsz=4096.
// task 0 xx (SYM: keep cb>=rb>>2 only), 1 yy (same), 2 xy,
// 3 xz (+colsum->s_zx), 4 yz (+colsum->s_zy).
// Fragment-native layout (R6): every MFMA A/B fragment is ONE coalesced
// global_load_dwordx4; no LDS staging, no hot-loop barriers.
// R13 = R11 structure (best measured: 4.07 ns/tile, VGPR 96, 128-thr blocks)
// + triangular xx/yy at fine granularity (R12's 256-thr blocks caused 2.06
// blocks/CU quantization + tail).  Kept sym blocks: 144/256 each; strictly-
// upper blocks emit colsums; reduce mirrors them as prefix-colsums.  Band
// blocks (rb>>2==cb) counted once via rowparts.  Grid 1056 x 128 thr.
// All reductions exclusive non-atomic stores (R3: atomics serialized).
// exp = __builtin_amdgcn_exp2f on prescaled inputs (1 inst).
// Timed-window floor: harness d_ws poison ~42us fixed.
// ---------------------------------------------------------------------------

typedef __attribute__((ext_vector_type(8))) short short8;   // 8 x bf16
typedef __attribute__((ext_vector_type(4))) float floatx4;  // MFMA acc

#define D   128
#define BSZ 4096
// grid: xx 144 + yy 144 + (xy,xz,yz) 3*256 = 1056 blocks of 128 threads
#define GRID_EXPSIM 1056

// ---------------------------------------------------------------------------
// Kernel 1: row-normalize fp32 -> bf16 into fragment-native layout,
// prescaled by sqrt(10*log2(e)).  One wave per row.  Also zeroes out[0].
// ---------------------------------------------------------------------------
__global__ __launch_bounds__(256) void normalize_kernel(
    const float* __restrict__ x, __hip_bfloat162* __restrict__ xnf2,
    float* __restrict__ out, int rows) {
  int tid = threadIdx.x;
  if (blockIdx.x == 0 && tid == 0) out[0] = 0.0f;

  int row  = blockIdx.x * 4 + (tid >> 6);
  int lane = tid & 63;
  if (row >= rows) return;
  const float2* xr = (const float2*)(x + (size_t)row * D);
  float2 v = xr[lane];
  float s = v.x * v.x + v.y * v.y;
#pragma unroll
  for (int off = 1; off < 64; off <<= 1) s += __shfl_xor(s, off, 64);
  // sqrt(10 / ln 2): dot(a,b) = 10*log2(e)*cos -> e^(10 cos) = exp2(dot)
  float scale = 3.7982825470322528f / fmaxf(sqrtf(s), 1e-12f);
  __hip_bfloat162 h;
  h.x = __float2bfloat16(v.x * scale);
  h.y = __float2bfloat16(v.y * scale);
  int g    = row >> 4;
  int kk   = lane >> 4;
  int quad = (lane >> 2) & 3;
  int jj   = lane & 3;
  xnf2[g * 1024 + kk * 256 + (quad * 16 + (row & 15)) * 4 + jj] = h;
}

// ---------------------------------------------------------------------------
// 16-col subtile epilogue for a 64-row wave: 16 exps, rowsum adds, optional
// colsum (quad-reduce -> LDS slot, written once), diag when st==st0+mi.
// C/D layout: col=lm, row=quad*4+reg  [m89-verified]
// ---------------------------------------------------------------------------
template <bool COL>
__device__ __forceinline__ void epi16(
    const floatx4 (&ac)[4], float (&rs)[4][4], int st,
    bool dgw, int st0, int rowg0, int quad, int lm, int w,
    float* __restrict__ diag_ptr, float* __restrict__ csLDS) {
  float cs = 0.f;
#pragma unroll
  for (int mi = 0; mi < 4; mi++) {
    bool dd = dgw && (st == st0 + mi);   // wave-uniform
#pragma unroll
    for (int r = 0; r < 4; r++) {
      float e = __builtin_amdgcn_exp2f(ac[mi][r]);  // v_exp_f32
      rs[mi][r] += e;
      if (COL) cs += e;
      if (dd && lm == quad * 4 + r)
        diag_ptr[rowg0 + mi * 16 + quad * 4 + r] = e;
    }
  }
  if (COL) {
    cs += __shfl_xor(cs, 16, 64);
    cs += __shfl_xor(cs, 32, 64);
    if (quad == 0) csLDS[w * 512 + st * 16 + lm] = cs;
  }
}

#define MFMA16(AC, BF)                                                       \
  _Pragma("unroll") for (int kk = 0; kk < 4; kk++)                           \
      _Pragma("unroll") for (int mi = 0; mi < 4; mi++)                       \
          AC[mi] = __builtin_amdgcn_mfma_f32_16x16x32_bf16(                  \
              afrag[mi][kk], BF[kk], (kk == 0) ? z4 : AC[mi], 0, 0, 0);

// ---------------------------------------------------------------------------
// Wave main loop: 64 rows x 512 cols as 32 subtiles of 16 cols, software-
// pipelined (epi of s-1 between MFMAs of s / loads of s+1).
// ---------------------------------------------------------------------------
template <bool COL>
__device__ __forceinline__ void wave_loop(
    const short8* __restrict__ xnf8, int gA, int gB0, int rowg0,
    int st0, bool dgw, int quad, int lm, int w, int lane,
    float (&rs)[4][4], float* __restrict__ diag_ptr,
    float* __restrict__ csLDS) {
  const floatx4 z4 = {0.f, 0.f, 0.f, 0.f};

  short8 afrag[4][4];
#pragma unroll
  for (int mi = 0; mi < 4; mi++)
#pragma unroll
    for (int kk = 0; kk < 4; kk++)
      afrag[mi][kk] = xnf8[(size_t)(gA + mi) * 256 + kk * 64 + lane];

  const short8* bp = xnf8 + (size_t)gB0 * 256 + lane;
  short8 bf0[4], bf1[4];
#pragma unroll
  for (int kk = 0; kk < 4; kk++) bf0[kk] = bp[kk * 64];
#pragma unroll
  for (int kk = 0; kk < 4; kk++) bf1[kk] = bp[256 + kk * 64];

  floatx4 ac0[4], ac1[4];
  MFMA16(ac0, bf0)   // st 0

#pragma unroll 1
  for (int k = 0; k < 15; k++) {
    int sB = 2 * k + 2;
    MFMA16(ac1, bf1)   // st sB-1
#pragma unroll
    for (int kk = 0; kk < 4; kk++) bf0[kk] = bp[(size_t)sB * 256 + kk * 64];
    epi16<COL>(ac0, rs, sB - 2, dgw, st0, rowg0, quad, lm, w, diag_ptr, csLDS);
    MFMA16(ac0, bf0)   // st sB
#pragma unroll
    for (int kk = 0; kk < 4; kk++) bf1[kk] = bp[(size_t)(sB + 1) * 256 + kk * 64];
    epi16<COL>(ac1, rs, sB - 1, dgw, st0, rowg0, quad, lm, w, diag_ptr, csLDS);
  }
  MFMA16(ac1, bf1)   // st 31
  epi16<COL>(ac0, rs, 30, dgw, st0, rowg0, quad, lm, w, diag_ptr, csLDS);
  epi16<COL>(ac1, rs, 31, dgw, st0, rowg0, quad, lm, w, diag_ptr, csLDS);
}

// ---------------------------------------------------------------------------
// Kernel 2: exp-sim.  block = 128 threads = 2 waves of 64 rows; block =
// (task, rb of 128 rows, cb of 512 cols).  Sym tasks keep cb >= rb>>2;
// colsum on sym only for strictly-upper (cb > rb>>2); band counted once.
// scol slots: 0 xx, 1 yy, 2 xz(zx), 3 yz(zy), each [32][4096].
// NOTE: plain __launch_bounds__ — min-waves cap spills (R2).
// ---------------------------------------------------------------------------
__global__ __launch_bounds__(128) void expsim_kernel(
    const short8* __restrict__ xnf8,
    float* __restrict__ srow,   // [5][64][8][64] exclusive (kept slots only)
    float* __restrict__ scol,   // [4][32][4096] exclusive (kept slots only)
    float* __restrict__ diag) { // [5][4096] exclusive
  __shared__ float csLDS[2 * 512];

  int tid = threadIdx.x;
  int bx  = blockIdx.x;

  int task, rb, cb;
  if (bx < 288) {              // symmetric tasks, 144 blocks each
    task = (bx >= 144) ? 1 : 0;
    int l = bx - task * 144;
    // groups g = rb>>2: 4 row-blocks each, count 4*(8-g)
    int g = 0;
    while (l >= 4 * (8 - g)) { l -= 4 * (8 - g); g++; }
    rb = 4 * g + l / (8 - g);
    cb = g + l % (8 - g);      // cb >= rb>>2
  } else {
    int local = bx - 288;
    task = 2 + (local >> 8);   // 256 blocks per task
    local &= 255;
    rb = local >> 3;           // 32 row-blocks of 128
    cb = local & 7;            // 8 col-strips of 512
  }

  const int aoff_t[5] = {0, 1, 0, 0, 1};
  const int boff_t[5] = {0, 1, 1, 2, 2};
  // colsum: tasks 3/4 always; xx/yy only strictly-upper blocks
  bool col_en = (task >= 3) || (task < 2 && cb > (rb >> 2));

  int w    = tid >> 6;         // wave 0..1
  int lane = tid & 63;
  int quad = lane >> 4;
  int lm   = lane & 15;
  int rowg0 = rb * 128 + w * 64;

  int gA  = aoff_t[task] * 256 + rb * 8 + w * 4;
  int gB0 = boff_t[task] * 256 + cb * 32;
  int st0 = rb * 8 + w * 4 - cb * 32;   // diag subtile (mi=0) if in range
  bool dgw = (st0 >= 0 && st0 < 32);

  float* diag_ptr = diag + task * BSZ;

  float rs[4][4];
#pragma unroll
  for (int mi = 0; mi < 4; mi++)
#pragma unroll
    for (int r = 0; r < 4; r++) rs[mi][r] = 0.0f;

  if (col_en)
    wave_loop<true>(xnf8, gA, gB0, rowg0, st0, dgw, quad, lm, w, lane, rs,
                    diag_ptr, csLDS);
  else
    wave_loop<false>(xnf8, gA, gB0, rowg0, st0, dgw, quad, lm, w, lane, rs,
                     diag_ptr, csLDS);

  // ---- row-sum flush: reduce over lm within quad, exclusive store ----
  float* sp = srow + (((size_t)task * 64 + rb * 2 + w) * 8 + cb) * 64;
#pragma unroll
  for (int mi = 0; mi < 4; mi++) {
#pragma unroll
    for (int r = 0; r < 4; r++) {
      float v = rs[mi][r];
      v += __shfl_xor(v, 1, 64);
      v += __shfl_xor(v, 2, 64);
      v += __shfl_xor(v, 4, 64);
      v += __shfl_xor(v, 8, 64);
      if (lm == 0) sp[mi * 16 + quad * 4 + r] = v;
    }
  }

  // ---- col-sum flush: one barrier, cross-wave LDS reduce, exclusive ----
  if (col_en) {
    __syncthreads();
    int sidx = (task < 2) ? task : task - 1;
    float* scp = scol + ((size_t)(sidx * 32 + rb)) * BSZ + cb * 512;
    for (int c = tid; c < 512; c += 128)
      scp[c] = csLDS[c] + csLDS[512 + c];
  }
}

// ---------------------------------------------------------------------------
// Kernel 3: final loss reduction.  16 blocks x 256 threads, one row each.
// xx/yy row i: rowparts over kept cbs (cb >= i>>9) + mirror prefix-colsums
// (rb' < 4*(i>>9)); unkept slots hold poison and are never read.
// ---------------------------------------------------------------------------
__global__ __launch_bounds__(256) void reduce_kernel(
    const float* __restrict__ srow, const float* __restrict__ scol,
    const float* __restrict__ diag, float* __restrict__ out) {
  int tid = threadIdx.x;
  int i   = blockIdx.x * 256 + tid;
  int strip64 = i >> 6, rloc = i & 63;
  int si = i >> 9;   // 512-col strip index (block-uniform)

  float s[5];
#pragma unroll
  for (int t = 0; t < 5; t++) {
    int cb0 = (t < 2) ? si : 0;
    float a = 0.f;
    for (int cbi = cb0; cbi < 8; cbi++)
      a += srow[(((size_t)t * 64 + strip64) * 8 + cbi) * 64 + rloc];
    s[t] = a;
  }
  // mirror prefix-colsums for xx/yy
  for (int rb2 = 0; rb2 < 4 * si; rb2++) {
    s[0] += scol[(size_t)(0 * 32 + rb2) * BSZ + i];
    s[1] += scol[(size_t)(1 * 32 + rb2) * BSZ + i];
  }
  float s_zx = 0.f, s_zy = 0.f;
#pragma unroll 8
  for (int rb2 = 0; rb2 < 32; rb2++) {
    s_zx += scol[(size_t)(2 * 32 + rb2) * BSZ + i];
    s_zy += scol[(size_t)(3 * 32 + rb2) * BSZ + i];
  }
  float d_xx = diag[0 * BSZ + i], d_yy = diag[1 * BSZ + i];
  float d_xy = diag[2 * BSZ + i], d_ax = diag[3 * BSZ + i];
  float d_ay = diag[4 * BSZ + i];

  float denom = (s[2] - d_xy) + (s[0] - d_xx) + (s[1] - d_yy);
  float tloc = -2.0f * __logf(d_xy / denom);
  tloc -= __logf(d_ax / (s[3] - d_ax));
  tloc -= __logf(d_ay / (s[4] - d_ay));
  tloc -= __logf(d_ax / (s_zx - d_ax));   // d_zx == d_ax
  tloc -= __logf(d_ay / (s_zy - d_ay));   // d_zy == d_ay

  __shared__ float red[256];
  red[tid] = tloc;
  __syncthreads();
  for (int st = 128; st > 0; st >>= 1) {
    if (tid < st) red[tid] += red[tid + st];
    __syncthreads();
  }
  if (tid == 0) atomicAdd(out, red[0] / (float)BSZ);
}

// ---------------------------------------------------------------------------
extern "C" void kernel_launch(void* const* d_in, const int* in_sizes, int n_in,
                              void* d_out, int out_size, void* d_ws, size_t ws_size,
                              hipStream_t stream) {
  const float* x = (const float*)d_in[0];
  int rows = in_sizes[0] / D;   // 12288

  char*  ws       = (char*)d_ws;
  short* xnf      = (short*)ws;                        // 12288*128 bf16: 3 MiB
  size_t xn_bytes = (size_t)rows * D * sizeof(short);
  float* srow     = (float*)(ws + xn_bytes);           // [5][64][8][64]: 640 KiB
  float* scol     = srow + 5 * 64 * 8 * 64;            // [4][32][4096]: 2 MiB
  float* diag     = scol + 4 * 32 * BSZ;               // [5][4096]: 80 KiB

  normalize_kernel<<<rows / 4, 256, 0, stream>>>(
      x, (__hip_bfloat162*)xnf, (float*)d_out, rows);
  expsim_kernel<<<GRID_EXPSIM, 128, 0, stream>>>(
      (const short8*)xnf, srow, scol, diag);
  reduce_kernel<<<16, 256, 0, stream>>>(srow, scol, diag, (float*)d_out);
}

// Round 14
// 94.165 us; speedup vs baseline: 1.1897x; 1.1897x over previous
//
#include <hip/hip_runtime.h>
#include <hip/hip_bf16.h>

// ---------------------------------------------------------------------------
// LossNet: x (12288,128) fp32 -> scalar loss.  bsz=4096.
// 5 matrices (zx/zy folded into colsums of xz/yz):
//   task 0 xx, 1 yy, 2 xy, 3 xz (+colsum->s_zx), 4 yz (+colsum->s_zy)
// Fragment-native layout (R6): every MFMA A/B fragment is ONE coalesced
// global_load_dwordx4; no LDS staging, no hot-loop barriers.
// R14 = R10 verbatim (measured best: 96.07 us total).  R12/R13 post-mortem:
// triangular xx/yy savings are grid-quantization-bound (1056 blocks -> same
// 5 rounds/CU as 1280, plus colsum overhead) -> regressed.  The ~4 ns per
// 128x64-tile expsim constant survived six structure falsifications
// (LDS-staged / direct / prefetch / reuse / pipelined / 64-row waves) ->
// structural plateau.  Timed window is ~44% fixed harness poison fill
// (268 MB @ ~80% HBM peak).  This locks in the best measured state.
// All reductions exclusive non-atomic stores (R3: atomics serialized).
// exp = __builtin_amdgcn_exp2f on prescaled inputs (1 inst).
// ---------------------------------------------------------------------------

typedef __attribute__((ext_vector_type(8))) short short8;   // 8 x bf16
typedef __attribute__((ext_vector_type(4))) float floatx4;  // MFMA acc

#define D   128
#define BSZ 4096
// expsim grid: 5 tasks x 32 rb(128 rows) x 8 cb(512 cols) = 1280 blocks
#define GRID_EXPSIM (5 * 32 * 8)

// ---------------------------------------------------------------------------
// Kernel 1: row-normalize fp32 -> bf16 into fragment-native layout,
// prescaled by sqrt(10*log2(e)).  One wave per row.  Also zeroes out[0].
// ---------------------------------------------------------------------------
__global__ __launch_bounds__(256) void normalize_kernel(
    const float* __restrict__ x, __hip_bfloat162* __restrict__ xnf2,
    float* __restrict__ out, int rows) {
  int tid = threadIdx.x;
  if (blockIdx.x == 0 && tid == 0) out[0] = 0.0f;

  int row  = blockIdx.x * 4 + (tid >> 6);
  int lane = tid & 63;
  if (row >= rows) return;
  const float2* xr = (const float2*)(x + (size_t)row * D);
  float2 v = xr[lane];
  float s = v.x * v.x + v.y * v.y;
#pragma unroll
  for (int off = 1; off < 64; off <<= 1) s += __shfl_xor(s, off, 64);
  // sqrt(10 / ln 2): dot(a,b) = 10*log2(e)*cos -> e^(10 cos) = exp2(dot)
  float scale = 3.7982825470322528f / fmaxf(sqrtf(s), 1e-12f);
  __hip_bfloat162 h;
  h.x = __float2bfloat16(v.x * scale);
  h.y = __float2bfloat16(v.y * scale);
  // fragment-native scatter: k0 = lane*2
  // short idx = g*2048 + kk*512 + (quad*16 + (row&15))*8 + j   (as bf162: /2)
  int g    = row >> 4;
  int kk   = lane >> 4;            // k0>>5
  int quad = (lane >> 2) & 3;      // (k0>>3)&3
  int jj   = lane & 3;             // (k0&7)/2
  xnf2[g * 1024 + kk * 256 + (quad * 16 + (row & 15)) * 4 + jj] = h;
}

// ---------------------------------------------------------------------------
// 16-col subtile epilogue for a 32-row wave: 8 exps, rowsum adds, optional
// colsum (quad-reduce -> LDS slot, written once), diag when st==st0+mi.
// C/D layout: col=lm, row=quad*4+reg  [m89-verified]
// ---------------------------------------------------------------------------
template <bool COL>
__device__ __forceinline__ void epi16(
    const floatx4 (&ac)[2], float (&rs)[2][4], int st,
    bool dgw, int st0, int rowg0, int quad, int lm, int w,
    float* __restrict__ diag_ptr, float* __restrict__ csLDS) {
  float cs = 0.f;
#pragma unroll
  for (int mi = 0; mi < 2; mi++) {
    bool dd = dgw && (st == st0 + mi);   // wave-uniform
#pragma unroll
    for (int r = 0; r < 4; r++) {
      float e = __builtin_amdgcn_exp2f(ac[mi][r]);  // v_exp_f32
      rs[mi][r] += e;
      if (COL) cs += e;
      if (dd && lm == quad * 4 + r)
        diag_ptr[rowg0 + mi * 16 + quad * 4 + r] = e;
    }
  }
  if (COL) {
    cs += __shfl_xor(cs, 16, 64);
    cs += __shfl_xor(cs, 32, 64);
    if (quad == 0) csLDS[w * 512 + st * 16 + lm] = cs;
  }
}

#define MFMA8(AC, BF)                                                        \
  _Pragma("unroll") for (int kk = 0; kk < 4; kk++)                           \
      _Pragma("unroll") for (int mi = 0; mi < 2; mi++)                       \
          AC[mi] = __builtin_amdgcn_mfma_f32_16x16x32_bf16(                  \
              afrag[mi][kk], BF[kk], (kk == 0) ? z4 : AC[mi], 0, 0, 0);

// ---------------------------------------------------------------------------
// Wave main loop: 32 rows x 512 cols as 32 subtiles of 16 cols, software-
// pipelined (epi of s-1 between MFMAs of s / loads of s+1).
// ---------------------------------------------------------------------------
template <bool COL>
__device__ __forceinline__ void wave_loop(
    const short8* __restrict__ xnf8, int gA, int gB0, int rowg0,
    int st0, bool dgw, int quad, int lm, int w, int lane,
    float (&rs)[2][4], float* __restrict__ diag_ptr,
    float* __restrict__ csLDS) {
  const floatx4 z4 = {0.f, 0.f, 0.f, 0.f};

  short8 afrag[2][4];
#pragma unroll
  for (int mi = 0; mi < 2; mi++)
#pragma unroll
    for (int kk = 0; kk < 4; kk++)
      afrag[mi][kk] = xnf8[(size_t)(gA + mi) * 256 + kk * 64 + lane];

  const short8* bp = xnf8 + (size_t)gB0 * 256 + lane;
  short8 bf0[4], bf1[4];
#pragma unroll
  for (int kk = 0; kk < 4; kk++) bf0[kk] = bp[kk * 64];
#pragma unroll
  for (int kk = 0; kk < 4; kk++) bf1[kk] = bp[256 + kk * 64];

  floatx4 ac0[2], ac1[2];
  MFMA8(ac0, bf0)   // st 0

#pragma unroll 1
  for (int k = 0; k < 15; k++) {
    int sB = 2 * k + 2;
    MFMA8(ac1, bf1)   // st sB-1
#pragma unroll
    for (int kk = 0; kk < 4; kk++) bf0[kk] = bp[(size_t)sB * 256 + kk * 64];
    epi16<COL>(ac0, rs, sB - 2, dgw, st0, rowg0, quad, lm, w, diag_ptr, csLDS);
    MFMA8(ac0, bf0)   // st sB
#pragma unroll
    for (int kk = 0; kk < 4; kk++) bf1[kk] = bp[(size_t)(sB + 1) * 256 + kk * 64];
    epi16<COL>(ac1, rs, sB - 1, dgw, st0, rowg0, quad, lm, w, diag_ptr, csLDS);
  }
  // tail: st 31 from bf1; epi st 30 (ac0), st 31 (ac1)
  MFMA8(ac1, bf1)
  epi16<COL>(ac0, rs, 30, dgw, st0, rowg0, quad, lm, w, diag_ptr, csLDS);
  epi16<COL>(ac1, rs, 31, dgw, st0, rowg0, quad, lm, w, diag_ptr, csLDS);
}

// ---------------------------------------------------------------------------
// Kernel 2: exp-sim.  block = (task, rb of 128 rows, cb of 512 cols);
// wave w owns rows rb*128+w*32..+32, all 512 cols.  4 waves share B (L1).
// NOTE: plain __launch_bounds__(256) — min-waves cap spills (R2).
// ---------------------------------------------------------------------------
__global__ __launch_bounds__(256) void expsim_kernel(
    const short8* __restrict__ xnf8,
    float* __restrict__ srow,   // [5][128][8][32] exclusive
    float* __restrict__ scol,   // [2][32][4096] exclusive
    float* __restrict__ diag) { // [5][4096] exclusive
  __shared__ float csLDS[4 * 512];   // colsum accum, tasks 3-4 only

  int tid = threadIdx.x;
  int bx  = blockIdx.x;
  int task = bx >> 8;          // 256 blocks per task
  int rem  = bx & 255;
  int rb   = rem >> 3;         // 32 row-blocks of 128
  int cb   = rem & 7;          // 8 col-strips of 512

  const int aoff_t[5] = {0, 1, 0, 0, 1};
  const int boff_t[5] = {0, 1, 1, 2, 2};
  bool col_en = (task >= 3);

  int w    = tid >> 6;
  int lane = tid & 63;
  int quad = lane >> 4;
  int lm   = lane & 15;
  int rowg0 = rb * 128 + w * 32;

  int gA  = aoff_t[task] * 256 + rb * 8 + w * 2;
  int gB0 = boff_t[task] * 256 + cb * 32;
  int st0 = rb * 8 + w * 2 - cb * 32;   // diag subtile (mi=0) if in range
  bool dgw = (st0 >= 0 && st0 < 32);

  float* diag_ptr = diag + task * BSZ;

  float rs[2][4];
#pragma unroll
  for (int mi = 0; mi < 2; mi++)
#pragma unroll
    for (int r = 0; r < 4; r++) rs[mi][r] = 0.0f;

  if (col_en)
    wave_loop<true>(xnf8, gA, gB0, rowg0, st0, dgw, quad, lm, w, lane, rs,
                    diag_ptr, csLDS);
  else
    wave_loop<false>(xnf8, gA, gB0, rowg0, st0, dgw, quad, lm, w, lane, rs,
                     diag_ptr, csLDS);

  // ---- row-sum flush: reduce over lm within quad, exclusive store ----
  float* sp = srow + (((size_t)task * 128 + rb * 4 + w) * 8 + cb) * 32;
#pragma unroll
  for (int mi = 0; mi < 2; mi++) {
#pragma unroll
    for (int r = 0; r < 4; r++) {
      float v = rs[mi][r];
      v += __shfl_xor(v, 1, 64);
      v += __shfl_xor(v, 2, 64);
      v += __shfl_xor(v, 4, 64);
      v += __shfl_xor(v, 8, 64);
      if (lm == 0) sp[mi * 16 + quad * 4 + r] = v;
    }
  }

  // ---- col-sum flush: one barrier, cross-wave LDS reduce, exclusive ----
  if (col_en) {
    __syncthreads();
    float* scp = scol + ((size_t)((task - 3) * 32 + rb)) * BSZ + cb * 512;
    for (int c = tid; c < 512; c += 256)
      scp[c] = csLDS[c] + csLDS[512 + c] + csLDS[1024 + c] + csLDS[1536 + c];
  }
}

// ---------------------------------------------------------------------------
// Kernel 3: final loss reduction.  16 blocks x 256 threads, one row each.
// ---------------------------------------------------------------------------
__global__ __launch_bounds__(256) void reduce_kernel(
    const float* __restrict__ srow, const float* __restrict__ scol,
    const float* __restrict__ diag, float* __restrict__ out) {
  int tid = threadIdx.x;
  int i   = blockIdx.x * 256 + tid;
  int strip = i >> 5, rloc = i & 31;

  float s[5];
#pragma unroll
  for (int t = 0; t < 5; t++) {
    float a = 0.f;
#pragma unroll
    for (int cb = 0; cb < 8; cb++)
      a += srow[(((size_t)t * 128 + strip) * 8 + cb) * 32 + rloc];
    s[t] = a;
  }
  float s_zx = 0.f, s_zy = 0.f;
#pragma unroll 8
  for (int rb = 0; rb < 32; rb++) {
    s_zx += scol[(size_t)rb * BSZ + i];
    s_zy += scol[(size_t)(32 + rb) * BSZ + i];
  }
  float d_xx = diag[0 * BSZ + i], d_yy = diag[1 * BSZ + i];
  float d_xy = diag[2 * BSZ + i], d_ax = diag[3 * BSZ + i];
  float d_ay = diag[4 * BSZ + i];

  float denom = (s[2] - d_xy) + (s[0] - d_xx) + (s[1] - d_yy);
  float tloc = -2.0f * __logf(d_xy / denom);
  tloc -= __logf(d_ax / (s[3] - d_ax));
  tloc -= __logf(d_ay / (s[4] - d_ay));
  tloc -= __logf(d_ax / (s_zx - d_ax));   // d_zx == d_ax
  tloc -= __logf(d_ay / (s_zy - d_ay));   // d_zy == d_ay

  __shared__ float red[256];
  red[tid] = tloc;
  __syncthreads();
  for (int st = 128; st > 0; st >>= 1) {
    if (tid < st) red[tid] += red[tid + st];
    __syncthreads();
  }
  if (tid == 0) atomicAdd(out, red[0] / (float)BSZ);
}

// ---------------------------------------------------------------------------
extern "C" void kernel_launch(void* const* d_in, const int* in_sizes, int n_in,
                              void* d_out, int out_size, void* d_ws, size_t ws_size,
                              hipStream_t stream) {
  const float* x = (const float*)d_in[0];
  int rows = in_sizes[0] / D;   // 12288

  char*  ws       = (char*)d_ws;
  short* xnf      = (short*)ws;                        // 12288*128 bf16: 3 MiB
  size_t xn_bytes = (size_t)rows * D * sizeof(short);
  float* srow     = (float*)(ws + xn_bytes);           // [5][128][8][32]: 640 KiB
  float* scol     = srow + 5 * 128 * 8 * 32;           // [2][32][4096]: 1 MiB
  float* diag     = scol + 2 * 32 * BSZ;               // [5][4096]: 80 KiB

  normalize_kernel<<<rows / 4, 256, 0, stream>>>(
      x, (__hip_bfloat162*)xnf, (float*)d_out, rows);
  expsim_kernel<<<GRID_EXPSIM, 256, 0, stream>>>(
      (const short8*)xnf, srow, scol, diag);
  reduce_kernel<<<16, 256, 0, stream>>>(srow, scol, diag, (float*)d_out);
}